// Round 21
// baseline (292.742 us; speedup 1.0000x reference)
//
#include <hip/hip_runtime.h>

#define Bn 8
#define Hn 128
#define Wn 128
#define Cn 192
#define Ln (Hn*Wn)          // 16384
#define Mn (Bn*Ln)          // 131072
#define FUn ((size_t)Mn*Cn) // 25,165,824 floats
#define BANKn ((size_t)Mn*96) // shorts per branch-bank
#define BN_RSQ 0.9999950000374997f   // 1/sqrt(1+1e-5)

typedef unsigned short ushort_t;
typedef __attribute__((ext_vector_type(8))) short short8;
typedef __attribute__((ext_vector_type(4))) float f32x4;
typedef __attribute__((ext_vector_type(4))) unsigned int uint4v;

static __device__ __forceinline__ float gelu_f(float x) {
    return 0.5f * x * (1.0f + erff(x * 0.7071067811865475f));
}
static __device__ __forceinline__ float gate1p(float x) {  // 1 + sigmoid(x)
    return 1.0f + 1.0f / (1.0f + __expf(-x));
}
static __device__ __forceinline__ unsigned short f2bf(float f) {  // RNE
    unsigned u = __float_as_uint(f);
    return (unsigned short)((u + 0x7FFFu + ((u >> 16) & 1u)) >> 16);
}
static __device__ __forceinline__ unsigned int pk2(float lo, float hi) {
    return (unsigned int)f2bf(lo) | ((unsigned int)f2bf(hi) << 16);
}
static __device__ __forceinline__ float bf2f(ushort_t u) {
    return __uint_as_float((unsigned)u << 16);
}

// ------- one-off: transpose+cast weights w[k*N+n] -> wT[n*K+k] (bf16) -------
__global__ __launch_bounds__(256) void cast_wT(const float* __restrict__ w,
        ushort_t* __restrict__ wT, int K, int N)
{
    int idx = blockIdx.x * 256 + threadIdx.x;
    if (idx < K * N) {
        int k = idx / N, n = idx - k * N;
        wT[(size_t)n * K + k] = f2bf(w[idx]);
    }
}

// ========== qkv GEMM, window-tiled, XCD-swizzled 1D grid ====================
// g = group*48 + sib*8 + w8 : 6 siblings (part,branch) of a window share
// g%8 (same XCD) and a 48-block dispatch span (temporal locality).
// B operand pre-transposed bf16: wT[col*192 + k].
__global__ __launch_bounds__(256) void qkv_mfma(const ushort_t* __restrict__ Ab,
        const ushort_t* __restrict__ BwT, const float* __restrict__ bias,
        ushort_t* __restrict__ Qp, ushort_t* __restrict__ Kp,
        ushort_t* __restrict__ Vp)
{
    __shared__ __align__(16) ushort_t smem[128 * 64 + 96 * 64];
    ushort_t* As = smem;
    ushort_t* Bs = smem + 128 * 64;
    ushort_t* St = smem;                   // Q/K: [t][104] = 13312 shorts
    ushort_t* Stv = smem;                  // V:   [col][136] = 13056 shorts
    const int g1d = blockIdx.x;            // 0..6143
    const int rem = g1d % 48;
    const int sib = rem >> 3;              // 0..5
    const int w8 = rem & 7;
    const int wid = (g1d / 48) * 8 + w8;   // b*128 + win
    const int br = sib & 1;
    const int partp = sib >> 1;            // 0=Q 1=K 2=V
    const int b = wid >> 7, win = wid & 127;
    const int n0g = partp * 192 + br * 96;
    ushort_t* dst = partp == 0 ? Qp : (partp == 1 ? Kp : Vp);
    ushort_t* bptr = dst + (br ? BANKn : 0);
    int hb, wb;
    if (br == 0) { hb = (win >> 3) * 8;  wb = (win & 7) * 16; }
    else         { hb = (win >> 4) * 16; wb = (win & 15) * 8; }
    const int tid = threadIdx.x;
    const int lane = tid & 63;
    const int wrow = (tid >> 6) * 32;
    const int r0 = lane >> 4, cl = lane & 15;
    f32x4 acc[2][6] = {};

    for (int ks = 0; ks < 3; ++ks) {
        const int k0 = ks * 64;
        if (ks) __syncthreads();
        #pragma unroll
        for (int i = 0; i < 2; ++i) {
            int s = tid + i * 256;
            int row = s >> 2, q = s & 3;   // row = token t
            int l = (br == 0) ? (hb + (row >> 4)) * Wn + wb + (row & 15)
                              : (hb + (row >> 3)) * Wn + wb + (row & 7);
            const ushort_t* src = Ab + (size_t)(b * Ln + l) * 192 + k0 + q * 16;
            uint4 u0 = *(const uint4*)(src);
            uint4 u1 = *(const uint4*)(src + 8);
            int r7 = row & 7;
            *(uint4*)&As[row * 64 + (((q * 2) ^ r7) * 8)] = u0;
            *(uint4*)&As[row * 64 + (((q * 2 + 1) ^ r7) * 8)] = u1;
        }
        #pragma unroll
        for (int i = 0; i < 3; ++i) {
            int f = tid + i * 256;                    // 0..767
            int col = f % 96, kslot = f / 96;
            uint4 wv = *(const uint4*)(BwT + (size_t)(n0g + col) * 192 + k0 + kslot * 8);
            *(uint4*)&Bs[col * 64 + ((kslot ^ (col & 7)) * 8)] = wv;
        }
        __syncthreads();
        #pragma unroll
        for (int kk = 0; kk < 2; ++kk) {
            int kslot = kk * 4 + r0;
            int ra0 = wrow + cl, ra1 = wrow + 16 + cl;
            short8 a0 = *(const short8*)&As[ra0 * 64 + ((kslot ^ (ra0 & 7)) * 8)];
            short8 a1 = *(const short8*)&As[ra1 * 64 + ((kslot ^ (ra1 & 7)) * 8)];
            #pragma unroll
            for (int n = 0; n < 6; ++n) {
                int col = n * 16 + cl;
                short8 bn = *(const short8*)&Bs[col * 64 + ((kslot ^ (col & 7)) * 8)];
                acc[0][n] = __builtin_amdgcn_mfma_f32_16x16x32_bf16(a0, bn, acc[0][n], 0, 0, 0);
                acc[1][n] = __builtin_amdgcn_mfma_f32_16x16x32_bf16(a1, bn, acc[1][n], 0, 0, 0);
            }
        }
    }
    float bv[6];
    #pragma unroll
    for (int n = 0; n < 6; ++n) bv[n] = bias[n0g + n * 16 + cl];
    __syncthreads();
    const size_t hbase = (size_t)wid * 3;
    if (partp < 2) {
        #pragma unroll
        for (int m = 0; m < 2; ++m)
            #pragma unroll
            for (int n = 0; n < 6; ++n)
                #pragma unroll
                for (int j = 0; j < 4; ++j) {
                    int t = wrow + m * 16 + r0 * 4 + j;
                    St[t * 104 + n * 16 + cl] = f2bf(acc[m][n][j] + bv[n]);
                }
        __syncthreads();
        #pragma unroll
        for (int i = 0; i < 6; ++i) {
            int f = tid + i * 256;                 // ch8(4) x t(128) x hd(3)
            int ch8 = f & 3, t = (f >> 2) & 127, hd = f >> 9;
            uint4 v = *(const uint4*)&St[t * 104 + hd * 32 + ch8 * 8];
            *(uint4*)(bptr + (hbase + hd) * 4096 + t * 32 + ch8 * 8) = v;
        }
    } else {
        #pragma unroll
        for (int m = 0; m < 2; ++m)
            #pragma unroll
            for (int n = 0; n < 6; ++n)
                #pragma unroll
                for (int j = 0; j < 4; ++j) {
                    int t = wrow + m * 16 + r0 * 4 + j;
                    Stv[(n * 16 + cl) * 136 + t] = f2bf(acc[m][n][j] + bv[n]);
                }
        __syncthreads();
        #pragma unroll
        for (int i = 0; i < 6; ++i) {
            int f = tid + i * 256;                 // t16(16) x ch(32) x hd(3)
            int t16 = f & 15, ch = (f >> 4) & 31, hd = f >> 9;
            uint4 v = *(const uint4*)&Stv[(hd * 32 + ch) * 136 + t16 * 8];
            *(uint4*)(bptr + (hbase + hd) * 4096 + ch * 128 + t16 * 8) = v;
        }
    }
}

// ====== proj GEMM: bf16 A (row-major) x pre-transposed bf16 B -> f32 out ====
__global__ __launch_bounds__(256) void proj_mfma(const ushort_t* __restrict__ Ab,
        const ushort_t* __restrict__ BwT, const float* __restrict__ bias,
        float* __restrict__ Cout)
{
    __shared__ __align__(16) ushort_t As[128 * 64];
    __shared__ __align__(16) ushort_t Bs[96 * 64];
    const int m0 = blockIdx.x * 128;
    const int n0 = blockIdx.y * 96;
    const int tid = threadIdx.x;
    const int lane = tid & 63;
    const int wrow = (tid >> 6) * 32;
    const int r0 = lane >> 4, cl = lane & 15;
    f32x4 acc[2][6] = {};

    for (int ks = 0; ks < 3; ++ks) {
        const int k0 = ks * 64;
        if (ks) __syncthreads();
        #pragma unroll
        for (int i = 0; i < 2; ++i) {
            int s = tid + i * 256;
            int row = s >> 2, q = s & 3;
            const ushort_t* src = Ab + (size_t)(m0 + row) * 192 + k0 + q * 16;
            uint4 u0 = *(const uint4*)(src);
            uint4 u1 = *(const uint4*)(src + 8);
            int r7 = row & 7;
            *(uint4*)&As[row * 64 + (((q * 2) ^ r7) * 8)] = u0;
            *(uint4*)&As[row * 64 + (((q * 2 + 1) ^ r7) * 8)] = u1;
        }
        #pragma unroll
        for (int i = 0; i < 3; ++i) {
            int f = tid + i * 256;
            int col = f % 96, kslot = f / 96;
            uint4 wv = *(const uint4*)(BwT + (size_t)(n0 + col) * 192 + k0 + kslot * 8);
            *(uint4*)&Bs[col * 64 + ((kslot ^ (col & 7)) * 8)] = wv;
        }
        __syncthreads();
        #pragma unroll
        for (int kk = 0; kk < 2; ++kk) {
            int kslot = kk * 4 + r0;
            int ra0 = wrow + cl, ra1 = wrow + 16 + cl;
            short8 a0 = *(const short8*)&As[ra0 * 64 + ((kslot ^ (ra0 & 7)) * 8)];
            short8 a1 = *(const short8*)&As[ra1 * 64 + ((kslot ^ (ra1 & 7)) * 8)];
            #pragma unroll
            for (int n = 0; n < 6; ++n) {
                int col = n * 16 + cl;
                short8 bn = *(const short8*)&Bs[col * 64 + ((kslot ^ (col & 7)) * 8)];
                acc[0][n] = __builtin_amdgcn_mfma_f32_16x16x32_bf16(a0, bn, acc[0][n], 0, 0, 0);
                acc[1][n] = __builtin_amdgcn_mfma_f32_16x16x32_bf16(a1, bn, acc[1][n], 0, 0, 0);
            }
        }
    }
    #pragma unroll
    for (int m = 0; m < 2; ++m) {
        #pragma unroll
        for (int n = 0; n < 6; ++n) {
            int col = n0 + n * 16 + cl;
            float bv = bias[col];
            #pragma unroll
            for (int j = 0; j < 4; ++j) {
                int row = m0 + wrow + m * 16 + r0 * 4 + j;
                Cout[(size_t)row * 192 + col] = acc[m][n][j] + bv;
            }
        }
    }
}

// ===== MFMA window attention on per-head banks; coalesced fragment loads ====
__global__ __launch_bounds__(256) void attn_mfma(const ushort_t* __restrict__ Qp,
        const ushort_t* __restrict__ Kp, const ushort_t* __restrict__ Vp,
        const float* __restrict__ gate_s, ushort_t* __restrict__ fu_b)
{
    const int widx = threadIdx.x >> 6;
    const int idx = blockIdx.x * 4 + widx;          // 0..12287
    const int jhalf = idx & 1;                      // sibling waves share a block
    const int sub0 = idx >> 1;                      // 0..6143
    const int branch = (sub0 >= 3072) ? 1 : 0;
    const int sub = sub0 - branch * 3072;
    const int head = sub >> 10;
    const int b = (sub >> 7) & 7;
    const int win = sub & 127;
    const int L = threadIdx.x & 63;
    const int g = L >> 4, q = L & 15;
    int hb, wb;
    if (branch == 0) { hb = (win >> 3) * 8;  wb = (win & 7) * 16; }
    else             { hb = (win >> 4) * 16; wb = (win & 15) * 8; }
    const int cf = branch * 96 + head * 32;         // fu channel base
    const int jbase = jhalf * 4;

    const size_t base = (branch ? BANKn : 0)
                      + ((size_t)(b * 128 + win) * 3 + head) * 4096;
    const ushort_t* Qw = Qp + base;
    const ushort_t* Kw = Kp + base;
    const ushort_t* Vw = Vp + base;                 // transposed [d=32][t=128]

    short8 kf[8], qf[4];
    #pragma unroll
    for (int i = 0; i < 8; ++i)
        kf[i] = *(const short8*)(Kw + (16 * i + q) * 32 + 8 * g);
    #pragma unroll
    for (int jj = 0; jj < 4; ++jj)
        qf[jj] = *(const short8*)(Qw + (16 * (jbase + jj) + q) * 32 + 8 * g);
    short8 vf[2][4];
    #pragma unroll
    for (int dblk = 0; dblk < 2; ++dblk)
        #pragma unroll
        for (int s = 0; s < 4; ++s)
            vf[dblk][s] = *(const short8*)(Vw + (16 * dblk + q) * 128 + 32 * s + 8 * g);

    const float SC = 0.5303300858899106f;   // 3/sqrt(32)
    const int src0 = q + ((g & 1) << 5);
    const bool thi = (g >> 1) != 0;
    const bool glo = (g < 2);
    #pragma unroll
    for (int jj = 0; jj < 4; ++jj) {
        const int j = jbase + jj;
        unsigned wA[8], wB[8];
        float ss = 0.0f;
        #pragma unroll
        for (int i = 0; i < 8; ++i) {
            f32x4 z = {};
            f32x4 S = __builtin_amdgcn_mfma_f32_16x16x32_bf16(kf[i], qf[jj], z, 0, 0, 0);
            float p0 = __expf(S[0] * SC), p1 = __expf(S[1] * SC);
            float p2 = __expf(S[2] * SC), p3 = __expf(S[3] * SC);
            ss += (p0 + p1) + (p2 + p3);
            wA[i] = pk2(p0, p1);
            wB[i] = pk2(p2, p3);
        }
        ss += __shfl_xor(ss, 16);
        ss += __shfl_xor(ss, 32);
        int l_own;
        if (branch == 0) l_own = (hb + j) * Wn + wb + q;
        else             l_own = (hb + 2 * j + (q >> 3)) * Wn + wb + (q & 7);
        float s_own = 3.0f * gate_s[(size_t)b * Ln + l_own] / ss;

        f32x4 O0 = {}, O1 = {};
        #pragma unroll
        for (int s = 0; s < 4; ++s) {
            unsigned a0  = (unsigned)__shfl((int)wA[2*s],     src0);
            unsigned b0  = (unsigned)__shfl((int)wB[2*s],     src0);
            unsigned a0h = (unsigned)__shfl((int)wA[2*s],     src0 + 16);
            unsigned b0h = (unsigned)__shfl((int)wB[2*s],     src0 + 16);
            unsigned a1  = (unsigned)__shfl((int)wA[2*s+1],   src0);
            unsigned b1  = (unsigned)__shfl((int)wB[2*s+1],   src0);
            unsigned a1h = (unsigned)__shfl((int)wA[2*s+1],   src0 + 16);
            unsigned b1h = (unsigned)__shfl((int)wB[2*s+1],   src0 + 16);
            uint4v B2u;
            B2u[0] = thi ? a1  : a0;
            B2u[1] = thi ? b1  : b0;
            B2u[2] = thi ? a1h : a0h;
            B2u[3] = thi ? b1h : b0h;
            short8 B2 = *(short8*)&B2u;
            O0 = __builtin_amdgcn_mfma_f32_16x16x32_bf16(vf[0][s], B2, O0, 0, 0, 0);
            O1 = __builtin_amdgcn_mfma_f32_16x16x32_bf16(vf[1][s], B2, O1, 0, 0, 0);
        }
        unsigned w0 = pk2(O0[0] * s_own, O0[1] * s_own);
        unsigned w1 = pk2(O0[2] * s_own, O0[3] * s_own);
        unsigned w2 = pk2(O1[0] * s_own, O1[1] * s_own);
        unsigned w3 = pk2(O1[2] * s_own, O1[3] * s_own);
        unsigned a0 = (unsigned)__shfl((int)w0, src0);
        unsigned a1 = (unsigned)__shfl((int)w1, src0);
        unsigned b0 = (unsigned)__shfl((int)w0, src0 + 16);
        unsigned b1 = (unsigned)__shfl((int)w1, src0 + 16);
        unsigned c0 = (unsigned)__shfl((int)w2, src0);
        unsigned c1 = (unsigned)__shfl((int)w3, src0);
        unsigned d0 = (unsigned)__shfl((int)w2, src0 + 16);
        unsigned d1 = (unsigned)__shfl((int)w3, src0 + 16);
        uint4 o = make_uint4(glo ? a0 : c0, glo ? a1 : c1,
                             glo ? b0 : d0, glo ? b1 : d1);
        *(uint4*)(fu_b + (size_t)(b * Ln + l_own) * 192 + cf + 8 * g) = o;
    }
}

// ---- conv1: dwconv3x3+BN+GELU, one row per thread (no serial chain) --------
__global__ __launch_bounds__(256) void conv1_k(const float* __restrict__ x,
        const float* __restrict__ wdw, const float* __restrict__ bdw,
        const float* __restrict__ g1, const float* __restrict__ be1,
        ushort_t* __restrict__ conv1b, ushort_t* __restrict__ xb,
        float* __restrict__ pooled16)
{
    int bc = blockIdx.x;                   // b*192 + c
    int rg = blockIdx.y;                   // 0..15
    int c = bc % 192;
    const float* plane = x + (size_t)bc * Ln;
    int t = threadIdx.x;
    int sx = t & 31, sy = t >> 5;          // 32 strips x 8 rows
    int w0 = sx * 4, h = rg * 8 + sy;
    float wk[9];
    #pragma unroll
    for (int i = 0; i < 9; ++i) wk[i] = wdw[c * 9 + i];
    float gb = g1[c] * BN_RSQ, bb = be1[c], bd = bdw[c];

    float a[3][6];
    #pragma unroll
    for (int i = 0; i < 3; ++i) {
        int hh = h - 1 + i;
        float4 m = make_float4(0.f, 0.f, 0.f, 0.f);
        if (hh >= 0 && hh < Hn)
            m = *(const float4*)(plane + hh * Wn + w0);
        float lf = __shfl_up(m.w, 1);
        float rt = __shfl_down(m.x, 1);
        a[i][0] = sx ? lf : 0.0f;
        a[i][1] = m.x; a[i][2] = m.y; a[i][3] = m.z; a[i][4] = m.w;
        a[i][5] = (sx < 31) ? rt : 0.0f;
    }
    *(uint2*)(xb + (size_t)bc * Ln + h * Wn + w0) =
        make_uint2(pk2(a[1][1], a[1][2]), pk2(a[1][3], a[1][4]));
    float psum = 0.0f;
    float o[4];
    #pragma unroll
    for (int p = 0; p < 4; ++p) {
        float s = wk[0] * a[0][p];
        s = fmaf(wk[1], a[0][p + 1], s);
        s = fmaf(wk[2], a[0][p + 2], s);
        s = fmaf(wk[3], a[1][p],     s);
        s = fmaf(wk[4], a[1][p + 1], s);
        s = fmaf(wk[5], a[1][p + 2], s);
        s = fmaf(wk[6], a[2][p],     s);
        s = fmaf(wk[7], a[2][p + 1], s);
        s = fmaf(wk[8], a[2][p + 2], s);
        float y = gelu_f((s + bd) * gb + bb);
        psum += y;
        o[p] = y;
    }
    *(uint2*)(conv1b + (size_t)bc * Ln + h * Wn + w0) =
        make_uint2(pk2(o[0], o[1]), pk2(o[2], o[3]));
    __shared__ float red[4];
    for (int off = 32; off; off >>= 1) psum += __shfl_down(psum, off);
    if ((t & 63) == 0) red[t >> 6] = psum;
    __syncthreads();
    if (t == 0)
        pooled16[bc * 16 + rg] = red[0] + red[1] + red[2] + red[3];
}

// ------- spatial gate: per-pixel 192->24->1 MLP on bf16 conv1 ---------------
__global__ __launch_bounds__(128) void spatial_gate_k(const ushort_t* __restrict__ conv1b,
        const float* __restrict__ ws1g, const float* __restrict__ bs1,
        const float* __restrict__ gsi, const float* __restrict__ besi,
        const float* __restrict__ ws2, const float* __restrict__ bs2,
        float* __restrict__ gate_s)
{
    int bh = blockIdx.x;                   // b*128 + h
    int b = bh >> 7, h = bh & 127;
    int w = threadIdx.x;
    __shared__ float ws1T[192 * 24];       // [c][o]
    for (int i = w; i < 192 * 24; i += 128) {
        int c = i / 24, o = i - c * 24;
        ws1T[i] = ws1g[o * 192 + c];
    }
    __syncthreads();
    float acc24[24] = {};
    const ushort_t* base = conv1b + (size_t)b * 192 * Ln + h * Wn + w;
    #pragma unroll 4
    for (int c = 0; c < 192; ++c) {
        float v = bf2f(base[(size_t)c * Ln]);
        const float4* wp = (const float4*)&ws1T[c * 24];
        #pragma unroll
        for (int o4 = 0; o4 < 6; ++o4) {
            float4 wv = wp[o4];
            acc24[o4*4+0] = fmaf(v, wv.x, acc24[o4*4+0]);
            acc24[o4*4+1] = fmaf(v, wv.y, acc24[o4*4+1]);
            acc24[o4*4+2] = fmaf(v, wv.z, acc24[o4*4+2]);
            acc24[o4*4+3] = fmaf(v, wv.w, acc24[o4*4+3]);
        }
    }
    float s2 = bs2[0];
    #pragma unroll
    for (int o = 0; o < 24; ++o)
        s2 = fmaf(gelu_f((acc24[o] + bs1[o]) * (gsi[o] * BN_RSQ) + besi[o]), ws2[o], s2);
    gate_s[(size_t)bh * 128 + w] = gate1p(s2);
}

// ------ channel gate: combine 16 pooled partials + 192->24->192 MLP --------
__global__ __launch_bounds__(192) void channel_gate_k(const float* __restrict__ pooled16,
        const float* __restrict__ w1, const float* __restrict__ b1,
        const float* __restrict__ g, const float* __restrict__ be,
        const float* __restrict__ w2, const float* __restrict__ b2,
        float* __restrict__ gate_c)
{
    int b = blockIdx.x, t = threadIdx.x;
    __shared__ float pl[192];
    __shared__ float h1[24];
    int bc = b * 192 + t;
    float s = 0.0f;
    #pragma unroll
    for (int i = 0; i < 16; ++i) s += pooled16[bc * 16 + i];
    pl[t] = s * (1.0f / Ln);
    __syncthreads();
    if (t < 24) {
        float a = b1[t];
        for (int c = 0; c < 192; ++c) a = fmaf(pl[c], w1[t * 192 + c], a);
        a = a * (g[t] * BN_RSQ) + be[t];
        h1[t] = gelu_f(a);
    }
    __syncthreads();
    float a = b2[t];
    #pragma unroll
    for (int o = 0; o < 24; ++o) a = fmaf(h1[o], w2[t * 24 + o], a);
    gate_c[b * 192 + t] = gate1p(a);
}

// ---- dwconv2: channels-last register 3x3 stencil, conflict-free LDS -------
__global__ __launch_bounds__(256) void dwconv2_k(const ushort_t* __restrict__ fu_b,
        const float* __restrict__ gate_c,
        const float* __restrict__ wdw, const float* __restrict__ bdw,
        const float* __restrict__ g2, const float* __restrict__ be2,
        ushort_t* __restrict__ out2b)
{
    int bh = blockIdx.x >> 1;              // b*128 + h
    int whalf = blockIdx.x & 1;
    int b = bh >> 7, h = bh & 127;
    int tid = threadIdx.x;
    __shared__ float cwp[24 * 105];        // [c8]{72 weights, 24 params}
    for (int idx = tid; idx < 24 * 96; idx += 256) {
        int c8 = idx / 96, r = idx - c8 * 96;
        float v;
        if (r < 72) {
            int i = r / 9, p = r - i * 9;
            v = wdw[(c8 * 8 + i) * 9 + p];
        } else {
            int r2 = r - 72;
            int i = r2 / 3, j = r2 - i * 3;
            int c = c8 * 8 + i;
            float A = g2[c] * BN_RSQ;
            v = (j == 0) ? A : (j == 1) ? fmaf(bdw[c], A, be2[c])
                                        : gate_c[b * 192 + c];
        }
        cwp[c8 * 105 + r] = v;
    }
    __syncthreads();
    const size_t outrow = (size_t)(b * Ln + h * Wn) * 192;
    for (int it = 0; it < 6; ++it) {
        int item = it * 256 + tid;          // 0..1535
        int w = whalf * 64 + item / 24;
        int c8 = item % 24;
        int co = c8 * 8;
        const float* wp = &cwp[c8 * 105];
        uint4 nb[3][3];
        #pragma unroll
        for (int r = 0; r < 3; ++r)
            #pragma unroll
            for (int d = 0; d < 3; ++d)
                nb[r][d] = make_uint4(0u, 0u, 0u, 0u);
        #pragma unroll
        for (int r = 0; r < 3; ++r) {
            int hh = h - 1 + r;
            if (hh < 0 || hh >= Hn) continue;
            const ushort_t* rp = fu_b + (size_t)(b * Ln + hh * Wn) * 192 + co;
            #pragma unroll
            for (int d = 0; d < 3; ++d) {
                int w2 = w - 1 + d;
                if (w2 < 0 || w2 >= Wn) continue;
                nb[r][d] = *(const uint4*)(rp + (size_t)w2 * 192);
            }
        }
        unsigned ou[4];
        #pragma unroll
        for (int i = 0; i < 8; ++i) {
            float s = 0.0f;
            #pragma unroll
            for (int r = 0; r < 3; ++r) {
                #pragma unroll
                for (int d = 0; d < 3; ++d) {
                    unsigned word = ((const unsigned*)&nb[r][d])[i >> 1];
                    float v = __uint_as_float((i & 1) ? (word & 0xffff0000u)
                                                      : (word << 16));
                    s = fmaf(wp[i * 9 + r * 3 + d], v, s);
                }
            }
            float A = wp[72 + i * 3];
            float Bc = wp[72 + i * 3 + 1];
            float G = wp[72 + i * 3 + 2];
            float y = gelu_f(fmaf(s, A, Bc)) * G;
            if (i & 1) ou[i >> 1] |= (unsigned)f2bf(y) << 16;
            else       ou[i >> 1] = (unsigned)f2bf(y);
        }
        *(uint4*)(out2b + outrow + (size_t)w * 192 + co) =
            make_uint4(ou[0], ou[1], ou[2], ou[3]);
    }
}

extern "C" void kernel_launch(void* const* d_in, const int* in_sizes, int n_in,
                              void* d_out, int out_size, void* d_ws, size_t ws_size,
                              hipStream_t stream) {
    (void)in_sizes; (void)n_in; (void)out_size; (void)ws_size;
    const float* x      = (const float*)d_in[0];
    const float* w_qkv  = (const float*)d_in[1];
    const float* b_qkv  = (const float*)d_in[2];
    const float* w_dw1  = (const float*)d_in[3];
    const float* b_dw1  = (const float*)d_in[4];
    const float* g_bn1  = (const float*)d_in[5];
    const float* be_bn1 = (const float*)d_in[6];
    const float* w_si1  = (const float*)d_in[7];
    const float* b_si1  = (const float*)d_in[8];
    const float* g_si   = (const float*)d_in[9];
    const float* be_si  = (const float*)d_in[10];
    const float* w_si2  = (const float*)d_in[11];
    const float* b_si2  = (const float*)d_in[12];
    const float* w_ci1  = (const float*)d_in[13];
    const float* b_ci1  = (const float*)d_in[14];
    const float* g_ci   = (const float*)d_in[15];
    const float* be_ci  = (const float*)d_in[16];
    const float* w_ci2  = (const float*)d_in[17];
    const float* b_ci2  = (const float*)d_in[18];
    const float* w_dw2  = (const float*)d_in[19];
    const float* b_dw2  = (const float*)d_in[20];
    const float* g_bn2  = (const float*)d_in[21];
    const float* be_bn2 = (const float*)d_in[22];
    const float* w_proj = (const float*)d_in[23];
    const float* b_proj = (const float*)d_in[24];

    float* ws = (float*)d_ws;
    ushort_t* conv1b = (ushort_t*)ws;
    ushort_t* Qp     = (ushort_t*)ws;
    ushort_t* Kp     = (ushort_t*)(ws + FUn / 2);
    ushort_t* out2b  = (ushort_t*)(ws + 8000000);
    float* gate_s    = ws + FUn;                       // B*L
    float* gate_c    = gate_s + (size_t)Bn * Ln;       // B*192
    float* pooled16  = gate_c + Bn * 192;              // B*192*16
    ushort_t* wqkvT  = (ushort_t*)(pooled16 + Bn * 192 * 16);  // 576*192 bf16
    ushort_t* wprojT = wqkvT + 576 * 192;              // 192*192 bf16
    ushort_t* xb     = (ushort_t*)d_out;
    ushort_t* fu_b   = (ushort_t*)d_out;
    ushort_t* Vp     = (ushort_t*)d_out + FUn;

    cast_wT<<<(192 * 576 + 255) / 256, 256, 0, stream>>>(w_qkv, wqkvT, 192, 576);
    cast_wT<<<(192 * 192 + 255) / 256, 256, 0, stream>>>(w_proj, wprojT, 192, 192);
    conv1_k<<<dim3(Bn * 192, 16), 256, 0, stream>>>(x, w_dw1, b_dw1, g_bn1, be_bn1,
                                                    conv1b, xb, pooled16);
    spatial_gate_k<<<Bn * Hn, 128, 0, stream>>>(conv1b, w_si1, b_si1, g_si, be_si,
                                                w_si2, b_si2, gate_s);
    channel_gate_k<<<Bn, 192, 0, stream>>>(pooled16, w_ci1, b_ci1, g_ci, be_ci,
                                           w_ci2, b_ci2, gate_c);
    qkv_mfma<<<6144, 256, 0, stream>>>(xb, wqkvT, b_qkv, Qp, Kp, Vp);
    attn_mfma<<<3072, 256, 0, stream>>>(Qp, Kp, Vp, gate_s, fu_b);
    dwconv2_k<<<Bn * Hn * 2, 256, 0, stream>>>(fu_b, gate_c,
                                               w_dw2, b_dw2, g_bn2, be_bn2, out2b);
    proj_mfma<<<dim3(Mn / 128, 2), 256, 0, stream>>>(out2b, wprojT, b_proj, (float*)d_out);
}

// Round 22
// 280.705 us; speedup vs baseline: 1.0429x; 1.0429x over previous
//
#include <hip/hip_runtime.h>

#define Bn 8
#define Hn 128
#define Wn 128
#define Cn 192
#define Ln (Hn*Wn)          // 16384
#define Mn (Bn*Ln)          // 131072
#define FUn ((size_t)Mn*Cn) // 25,165,824 floats
#define BANKn ((size_t)Mn*96) // shorts per branch-bank
#define BN_RSQ 0.9999950000374997f   // 1/sqrt(1+1e-5)

typedef unsigned short ushort_t;
typedef __attribute__((ext_vector_type(8))) short short8;
typedef __attribute__((ext_vector_type(4))) float f32x4;
typedef __attribute__((ext_vector_type(4))) unsigned int uint4v;

static __device__ __forceinline__ float gelu_f(float x) {
    return 0.5f * x * (1.0f + erff(x * 0.7071067811865475f));
}
static __device__ __forceinline__ float gate1p(float x) {  // 1 + sigmoid(x)
    return 1.0f + 1.0f / (1.0f + __expf(-x));
}
static __device__ __forceinline__ unsigned short f2bf(float f) {  // RNE
    unsigned u = __float_as_uint(f);
    return (unsigned short)((u + 0x7FFFu + ((u >> 16) & 1u)) >> 16);
}
static __device__ __forceinline__ unsigned int pk2(float lo, float hi) {
    return (unsigned int)f2bf(lo) | ((unsigned int)f2bf(hi) << 16);
}
static __device__ __forceinline__ float bf2f(ushort_t u) {
    return __uint_as_float((unsigned)u << 16);
}

// ========== qkv GEMM, window-tiled, XCD-swizzled 1D grid ====================
__global__ __launch_bounds__(256) void qkv_mfma(const ushort_t* __restrict__ Ab,
        const ushort_t* __restrict__ BwT, const float* __restrict__ bias,
        ushort_t* __restrict__ Qp, ushort_t* __restrict__ Kp,
        ushort_t* __restrict__ Vp)
{
    __shared__ __align__(16) ushort_t smem[128 * 64 + 96 * 64];
    ushort_t* As = smem;
    ushort_t* Bs = smem + 128 * 64;
    ushort_t* St = smem;                   // Q/K: [t][104] = 13312 shorts
    ushort_t* Stv = smem;                  // V:   [col][136] = 13056 shorts
    const int g1d = blockIdx.x;            // 0..6143
    const int rem = g1d % 48;
    const int sib = rem >> 3;              // 0..5
    const int w8 = rem & 7;
    const int wid = (g1d / 48) * 8 + w8;   // b*128 + win
    const int br = sib & 1;
    const int partp = sib >> 1;            // 0=Q 1=K 2=V
    const int b = wid >> 7, win = wid & 127;
    const int n0g = partp * 192 + br * 96;
    ushort_t* dst = partp == 0 ? Qp : (partp == 1 ? Kp : Vp);
    ushort_t* bptr = dst + (br ? BANKn : 0);
    int hb, wb;
    if (br == 0) { hb = (win >> 3) * 8;  wb = (win & 7) * 16; }
    else         { hb = (win >> 4) * 16; wb = (win & 15) * 8; }
    const int tid = threadIdx.x;
    const int lane = tid & 63;
    const int wrow = (tid >> 6) * 32;
    const int r0 = lane >> 4, cl = lane & 15;
    f32x4 acc[2][6] = {};

    for (int ks = 0; ks < 3; ++ks) {
        const int k0 = ks * 64;
        if (ks) __syncthreads();
        #pragma unroll
        for (int i = 0; i < 2; ++i) {
            int s = tid + i * 256;
            int row = s >> 2, q = s & 3;   // row = token t
            int l = (br == 0) ? (hb + (row >> 4)) * Wn + wb + (row & 15)
                              : (hb + (row >> 3)) * Wn + wb + (row & 7);
            const ushort_t* src = Ab + (size_t)(b * Ln + l) * 192 + k0 + q * 16;
            uint4 u0 = *(const uint4*)(src);
            uint4 u1 = *(const uint4*)(src + 8);
            int r7 = row & 7;
            *(uint4*)&As[row * 64 + (((q * 2) ^ r7) * 8)] = u0;
            *(uint4*)&As[row * 64 + (((q * 2 + 1) ^ r7) * 8)] = u1;
        }
        #pragma unroll
        for (int i = 0; i < 3; ++i) {
            int f = tid + i * 256;                    // 0..767
            int col = f % 96, kslot = f / 96;
            uint4 wv = *(const uint4*)(BwT + (size_t)(n0g + col) * 192 + k0 + kslot * 8);
            *(uint4*)&Bs[col * 64 + ((kslot ^ (col & 7)) * 8)] = wv;
        }
        __syncthreads();
        #pragma unroll
        for (int kk = 0; kk < 2; ++kk) {
            int kslot = kk * 4 + r0;
            int ra0 = wrow + cl, ra1 = wrow + 16 + cl;
            short8 a0 = *(const short8*)&As[ra0 * 64 + ((kslot ^ (ra0 & 7)) * 8)];
            short8 a1 = *(const short8*)&As[ra1 * 64 + ((kslot ^ (ra1 & 7)) * 8)];
            #pragma unroll
            for (int n = 0; n < 6; ++n) {
                int col = n * 16 + cl;
                short8 bn = *(const short8*)&Bs[col * 64 + ((kslot ^ (col & 7)) * 8)];
                acc[0][n] = __builtin_amdgcn_mfma_f32_16x16x32_bf16(a0, bn, acc[0][n], 0, 0, 0);
                acc[1][n] = __builtin_amdgcn_mfma_f32_16x16x32_bf16(a1, bn, acc[1][n], 0, 0, 0);
            }
        }
    }
    float bv[6];
    #pragma unroll
    for (int n = 0; n < 6; ++n) bv[n] = bias[n0g + n * 16 + cl];
    __syncthreads();
    const size_t hbase = (size_t)wid * 3;
    if (partp < 2) {
        #pragma unroll
        for (int m = 0; m < 2; ++m)
            #pragma unroll
            for (int n = 0; n < 6; ++n)
                #pragma unroll
                for (int j = 0; j < 4; ++j) {
                    int t = wrow + m * 16 + r0 * 4 + j;
                    St[t * 104 + n * 16 + cl] = f2bf(acc[m][n][j] + bv[n]);
                }
        __syncthreads();
        #pragma unroll
        for (int i = 0; i < 6; ++i) {
            int f = tid + i * 256;                 // ch8(4) x t(128) x hd(3)
            int ch8 = f & 3, t = (f >> 2) & 127, hd = f >> 9;
            uint4 v = *(const uint4*)&St[t * 104 + hd * 32 + ch8 * 8];
            *(uint4*)(bptr + (hbase + hd) * 4096 + t * 32 + ch8 * 8) = v;
        }
    } else {
        #pragma unroll
        for (int m = 0; m < 2; ++m)
            #pragma unroll
            for (int n = 0; n < 6; ++n)
                #pragma unroll
                for (int j = 0; j < 4; ++j) {
                    int t = wrow + m * 16 + r0 * 4 + j;
                    Stv[(n * 16 + cl) * 136 + t] = f2bf(acc[m][n][j] + bv[n]);
                }
        __syncthreads();
        #pragma unroll
        for (int i = 0; i < 6; ++i) {
            int f = tid + i * 256;                 // t16(16) x ch(32) x hd(3)
            int t16 = f & 15, ch = (f >> 4) & 31, hd = f >> 9;
            uint4 v = *(const uint4*)&Stv[(hd * 32 + ch) * 136 + t16 * 8];
            *(uint4*)(bptr + (hbase + hd) * 4096 + ch * 128 + t16 * 8) = v;
        }
    }
}

// ====== proj GEMM: bf16 A (row-major) x pre-transposed bf16 B -> f32 out ====
__global__ __launch_bounds__(256) void proj_mfma(const ushort_t* __restrict__ Ab,
        const ushort_t* __restrict__ BwT, const float* __restrict__ bias,
        float* __restrict__ Cout)
{
    __shared__ __align__(16) ushort_t As[128 * 64];
    __shared__ __align__(16) ushort_t Bs[96 * 64];
    const int m0 = blockIdx.x * 128;
    const int n0 = blockIdx.y * 96;
    const int tid = threadIdx.x;
    const int lane = tid & 63;
    const int wrow = (tid >> 6) * 32;
    const int r0 = lane >> 4, cl = lane & 15;
    f32x4 acc[2][6] = {};

    for (int ks = 0; ks < 3; ++ks) {
        const int k0 = ks * 64;
        if (ks) __syncthreads();
        #pragma unroll
        for (int i = 0; i < 2; ++i) {
            int s = tid + i * 256;
            int row = s >> 2, q = s & 3;
            const ushort_t* src = Ab + (size_t)(m0 + row) * 192 + k0 + q * 16;
            uint4 u0 = *(const uint4*)(src);
            uint4 u1 = *(const uint4*)(src + 8);
            int r7 = row & 7;
            *(uint4*)&As[row * 64 + (((q * 2) ^ r7) * 8)] = u0;
            *(uint4*)&As[row * 64 + (((q * 2 + 1) ^ r7) * 8)] = u1;
        }
        #pragma unroll
        for (int i = 0; i < 3; ++i) {
            int f = tid + i * 256;
            int col = f % 96, kslot = f / 96;
            uint4 wv = *(const uint4*)(BwT + (size_t)(n0 + col) * 192 + k0 + kslot * 8);
            *(uint4*)&Bs[col * 64 + ((kslot ^ (col & 7)) * 8)] = wv;
        }
        __syncthreads();
        #pragma unroll
        for (int kk = 0; kk < 2; ++kk) {
            int kslot = kk * 4 + r0;
            int ra0 = wrow + cl, ra1 = wrow + 16 + cl;
            short8 a0 = *(const short8*)&As[ra0 * 64 + ((kslot ^ (ra0 & 7)) * 8)];
            short8 a1 = *(const short8*)&As[ra1 * 64 + ((kslot ^ (ra1 & 7)) * 8)];
            #pragma unroll
            for (int n = 0; n < 6; ++n) {
                int col = n * 16 + cl;
                short8 bn = *(const short8*)&Bs[col * 64 + ((kslot ^ (col & 7)) * 8)];
                acc[0][n] = __builtin_amdgcn_mfma_f32_16x16x32_bf16(a0, bn, acc[0][n], 0, 0, 0);
                acc[1][n] = __builtin_amdgcn_mfma_f32_16x16x32_bf16(a1, bn, acc[1][n], 0, 0, 0);
            }
        }
    }
    #pragma unroll
    for (int m = 0; m < 2; ++m) {
        #pragma unroll
        for (int n = 0; n < 6; ++n) {
            int col = n0 + n * 16 + cl;
            float bv = bias[col];
            #pragma unroll
            for (int j = 0; j < 4; ++j) {
                int row = m0 + wrow + m * 16 + r0 * 4 + j;
                Cout[(size_t)row * 192 + col] = acc[m][n][j] + bv;
            }
        }
    }
}

// ===== MFMA window attention on per-head banks; coalesced fragment loads ====
__global__ __launch_bounds__(256) void attn_mfma(const ushort_t* __restrict__ Qp,
        const ushort_t* __restrict__ Kp, const ushort_t* __restrict__ Vp,
        const float* __restrict__ gate_s, ushort_t* __restrict__ fu_b)
{
    const int widx = threadIdx.x >> 6;
    const int idx = blockIdx.x * 4 + widx;          // 0..12287
    const int jhalf = idx & 1;                      // sibling waves share a block
    const int sub0 = idx >> 1;                      // 0..6143
    const int branch = (sub0 >= 3072) ? 1 : 0;
    const int sub = sub0 - branch * 3072;
    const int head = sub >> 10;
    const int b = (sub >> 7) & 7;
    const int win = sub & 127;
    const int L = threadIdx.x & 63;
    const int g = L >> 4, q = L & 15;
    int hb, wb;
    if (branch == 0) { hb = (win >> 3) * 8;  wb = (win & 7) * 16; }
    else             { hb = (win >> 4) * 16; wb = (win & 15) * 8; }
    const int cf = branch * 96 + head * 32;         // fu channel base
    const int jbase = jhalf * 4;

    const size_t base = (branch ? BANKn : 0)
                      + ((size_t)(b * 128 + win) * 3 + head) * 4096;
    const ushort_t* Qw = Qp + base;
    const ushort_t* Kw = Kp + base;
    const ushort_t* Vw = Vp + base;                 // transposed [d=32][t=128]

    short8 kf[8], qf[4];
    #pragma unroll
    for (int i = 0; i < 8; ++i)
        kf[i] = *(const short8*)(Kw + (16 * i + q) * 32 + 8 * g);
    #pragma unroll
    for (int jj = 0; jj < 4; ++jj)
        qf[jj] = *(const short8*)(Qw + (16 * (jbase + jj) + q) * 32 + 8 * g);
    short8 vf[2][4];
    #pragma unroll
    for (int dblk = 0; dblk < 2; ++dblk)
        #pragma unroll
        for (int s = 0; s < 4; ++s)
            vf[dblk][s] = *(const short8*)(Vw + (16 * dblk + q) * 128 + 32 * s + 8 * g);

    const float SC = 0.5303300858899106f;   // 3/sqrt(32)
    const int src0 = q + ((g & 1) << 5);
    const bool thi = (g >> 1) != 0;
    const bool glo = (g < 2);
    #pragma unroll
    for (int jj = 0; jj < 4; ++jj) {
        const int j = jbase + jj;
        unsigned wA[8], wB[8];
        float ss = 0.0f;
        #pragma unroll
        for (int i = 0; i < 8; ++i) {
            f32x4 z = {};
            f32x4 S = __builtin_amdgcn_mfma_f32_16x16x32_bf16(kf[i], qf[jj], z, 0, 0, 0);
            float p0 = __expf(S[0] * SC), p1 = __expf(S[1] * SC);
            float p2 = __expf(S[2] * SC), p3 = __expf(S[3] * SC);
            ss += (p0 + p1) + (p2 + p3);
            wA[i] = pk2(p0, p1);
            wB[i] = pk2(p2, p3);
        }
        ss += __shfl_xor(ss, 16);
        ss += __shfl_xor(ss, 32);
        int l_own;
        if (branch == 0) l_own = (hb + j) * Wn + wb + q;
        else             l_own = (hb + 2 * j + (q >> 3)) * Wn + wb + (q & 7);
        float s_own = 3.0f * gate_s[(size_t)b * Ln + l_own] / ss;

        f32x4 O0 = {}, O1 = {};
        #pragma unroll
        for (int s = 0; s < 4; ++s) {
            unsigned a0  = (unsigned)__shfl((int)wA[2*s],     src0);
            unsigned b0  = (unsigned)__shfl((int)wB[2*s],     src0);
            unsigned a0h = (unsigned)__shfl((int)wA[2*s],     src0 + 16);
            unsigned b0h = (unsigned)__shfl((int)wB[2*s],     src0 + 16);
            unsigned a1  = (unsigned)__shfl((int)wA[2*s+1],   src0);
            unsigned b1  = (unsigned)__shfl((int)wB[2*s+1],   src0);
            unsigned a1h = (unsigned)__shfl((int)wA[2*s+1],   src0 + 16);
            unsigned b1h = (unsigned)__shfl((int)wB[2*s+1],   src0 + 16);
            uint4v B2u;
            B2u[0] = thi ? a1  : a0;
            B2u[1] = thi ? b1  : b0;
            B2u[2] = thi ? a1h : a0h;
            B2u[3] = thi ? b1h : b0h;
            short8 B2 = *(short8*)&B2u;
            O0 = __builtin_amdgcn_mfma_f32_16x16x32_bf16(vf[0][s], B2, O0, 0, 0, 0);
            O1 = __builtin_amdgcn_mfma_f32_16x16x32_bf16(vf[1][s], B2, O1, 0, 0, 0);
        }
        unsigned w0 = pk2(O0[0] * s_own, O0[1] * s_own);
        unsigned w1 = pk2(O0[2] * s_own, O0[3] * s_own);
        unsigned w2 = pk2(O1[0] * s_own, O1[1] * s_own);
        unsigned w3 = pk2(O1[2] * s_own, O1[3] * s_own);
        unsigned a0 = (unsigned)__shfl((int)w0, src0);
        unsigned a1 = (unsigned)__shfl((int)w1, src0);
        unsigned b0 = (unsigned)__shfl((int)w0, src0 + 16);
        unsigned b1 = (unsigned)__shfl((int)w1, src0 + 16);
        unsigned c0 = (unsigned)__shfl((int)w2, src0);
        unsigned c1 = (unsigned)__shfl((int)w3, src0);
        unsigned d0 = (unsigned)__shfl((int)w2, src0 + 16);
        unsigned d1 = (unsigned)__shfl((int)w3, src0 + 16);
        uint4 o = make_uint4(glo ? a0 : c0, glo ? a1 : c1,
                             glo ? b0 : d0, glo ? b1 : d1);
        *(uint4*)(fu_b + (size_t)(b * Ln + l_own) * 192 + cf + 8 * g) = o;
    }
}

// ---- conv1: dwconv3x3+BN+GELU (one row/thread) + fused weight transposes ---
__global__ __launch_bounds__(256) void conv1_k(const float* __restrict__ x,
        const float* __restrict__ wdw, const float* __restrict__ bdw,
        const float* __restrict__ g1, const float* __restrict__ be1,
        const float* __restrict__ w_qkv, const float* __restrict__ w_proj,
        ushort_t* __restrict__ conv1b, ushort_t* __restrict__ xb,
        ushort_t* __restrict__ wqkvT, ushort_t* __restrict__ wprojT,
        float* __restrict__ pooled16)
{
    // one-off weight transpose+cast, done by the y==0 slice (runs before qkv)
    if (blockIdx.y == 0) {
        int gid = blockIdx.x * 256 + threadIdx.x;   // 0..393215
        if (gid < 192 * 576) {
            int k = gid / 576, n = gid - k * 576;
            wqkvT[(size_t)n * 192 + k] = f2bf(w_qkv[gid]);
        } else if (gid < 192 * 576 + 192 * 192) {
            int g2 = gid - 192 * 576;
            int k = g2 / 192, n = g2 - k * 192;
            wprojT[(size_t)n * 192 + k] = f2bf(w_proj[g2]);
        }
    }
    int bc = blockIdx.x;                   // b*192 + c
    int rg = blockIdx.y;                   // 0..15
    int c = bc % 192;
    const float* plane = x + (size_t)bc * Ln;
    int t = threadIdx.x;
    int sx = t & 31, sy = t >> 5;          // 32 strips x 8 rows
    int w0 = sx * 4, h = rg * 8 + sy;
    float wk[9];
    #pragma unroll
    for (int i = 0; i < 9; ++i) wk[i] = wdw[c * 9 + i];
    float gb = g1[c] * BN_RSQ, bb = be1[c], bd = bdw[c];

    float a[3][6];
    #pragma unroll
    for (int i = 0; i < 3; ++i) {
        int hh = h - 1 + i;
        float4 m = make_float4(0.f, 0.f, 0.f, 0.f);
        if (hh >= 0 && hh < Hn)
            m = *(const float4*)(plane + hh * Wn + w0);
        float lf = __shfl_up(m.w, 1);
        float rt = __shfl_down(m.x, 1);
        a[i][0] = sx ? lf : 0.0f;
        a[i][1] = m.x; a[i][2] = m.y; a[i][3] = m.z; a[i][4] = m.w;
        a[i][5] = (sx < 31) ? rt : 0.0f;
    }
    *(uint2*)(xb + (size_t)bc * Ln + h * Wn + w0) =
        make_uint2(pk2(a[1][1], a[1][2]), pk2(a[1][3], a[1][4]));
    float psum = 0.0f;
    float o[4];
    #pragma unroll
    for (int p = 0; p < 4; ++p) {
        float s = wk[0] * a[0][p];
        s = fmaf(wk[1], a[0][p + 1], s);
        s = fmaf(wk[2], a[0][p + 2], s);
        s = fmaf(wk[3], a[1][p],     s);
        s = fmaf(wk[4], a[1][p + 1], s);
        s = fmaf(wk[5], a[1][p + 2], s);
        s = fmaf(wk[6], a[2][p],     s);
        s = fmaf(wk[7], a[2][p + 1], s);
        s = fmaf(wk[8], a[2][p + 2], s);
        float y = gelu_f((s + bd) * gb + bb);
        psum += y;
        o[p] = y;
    }
    *(uint2*)(conv1b + (size_t)bc * Ln + h * Wn + w0) =
        make_uint2(pk2(o[0], o[1]), pk2(o[2], o[3]));
    __shared__ float red[4];
    for (int off = 32; off; off >>= 1) psum += __shfl_down(psum, off);
    if ((t & 63) == 0) red[t >> 6] = psum;
    __syncthreads();
    if (t == 0)
        pooled16[bc * 16 + rg] = red[0] + red[1] + red[2] + red[3];
}

// ------- merged gates: blocks 0..1023 spatial rows, 1024..1031 channel ------
__global__ __launch_bounds__(192) void gates_k(const ushort_t* __restrict__ conv1b,
        const float* __restrict__ pooled16,
        const float* __restrict__ ws1g, const float* __restrict__ bs1,
        const float* __restrict__ gsi, const float* __restrict__ besi,
        const float* __restrict__ ws2, const float* __restrict__ bs2,
        const float* __restrict__ w1, const float* __restrict__ b1,
        const float* __restrict__ gci, const float* __restrict__ beci,
        const float* __restrict__ w2, const float* __restrict__ b2,
        float* __restrict__ gate_s, float* __restrict__ gate_c)
{
    int blk = blockIdx.x;
    int tid = threadIdx.x;
    if (blk < Bn * Hn) {                   // ---- spatial gate row ----
        int b = blk >> 7, h = blk & 127;
        __shared__ float ws1T[192 * 24];   // [c][o]
        for (int i = tid; i < 192 * 24; i += 192) {
            int c = i / 24, o = i - c * 24;
            ws1T[i] = ws1g[o * 192 + c];
        }
        __syncthreads();
        if (tid < 128) {
            int w = tid;
            float acc24[24] = {};
            const ushort_t* base = conv1b + (size_t)b * 192 * Ln + h * Wn + w;
            #pragma unroll 4
            for (int c = 0; c < 192; ++c) {
                float v = bf2f(base[(size_t)c * Ln]);
                const float4* wp = (const float4*)&ws1T[c * 24];
                #pragma unroll
                for (int o4 = 0; o4 < 6; ++o4) {
                    float4 wv = wp[o4];
                    acc24[o4*4+0] = fmaf(v, wv.x, acc24[o4*4+0]);
                    acc24[o4*4+1] = fmaf(v, wv.y, acc24[o4*4+1]);
                    acc24[o4*4+2] = fmaf(v, wv.z, acc24[o4*4+2]);
                    acc24[o4*4+3] = fmaf(v, wv.w, acc24[o4*4+3]);
                }
            }
            float s2 = bs2[0];
            #pragma unroll
            for (int o = 0; o < 24; ++o)
                s2 = fmaf(gelu_f((acc24[o] + bs1[o]) * (gsi[o] * BN_RSQ) + besi[o]),
                          ws2[o], s2);
            gate_s[(size_t)blk * 128 + w] = gate1p(s2);
        }
    } else {                               // ---- channel gate batch ----
        int b = blk - Bn * Hn;
        __shared__ float pl[192];
        __shared__ float h1[24];
        int bc = b * 192 + tid;
        float s = 0.0f;
        #pragma unroll
        for (int i = 0; i < 16; ++i) s += pooled16[bc * 16 + i];
        pl[tid] = s * (1.0f / Ln);
        __syncthreads();
        if (tid < 24) {
            float a = b1[tid];
            for (int c = 0; c < 192; ++c) a = fmaf(pl[c], w1[tid * 192 + c], a);
            a = a * (gci[tid] * BN_RSQ) + beci[tid];
            h1[tid] = gelu_f(a);
        }
        __syncthreads();
        float a = b2[tid];
        #pragma unroll
        for (int o = 0; o < 24; ++o) a = fmaf(h1[o], w2[tid * 24 + o], a);
        gate_c[b * 192 + tid] = gate1p(a);
    }
}

// ---- dwconv2: channels-last register 3x3 stencil, conflict-free LDS -------
__global__ __launch_bounds__(256) void dwconv2_k(const ushort_t* __restrict__ fu_b,
        const float* __restrict__ gate_c,
        const float* __restrict__ wdw, const float* __restrict__ bdw,
        const float* __restrict__ g2, const float* __restrict__ be2,
        ushort_t* __restrict__ out2b)
{
    int bh = blockIdx.x >> 1;              // b*128 + h
    int whalf = blockIdx.x & 1;
    int b = bh >> 7, h = bh & 127;
    int tid = threadIdx.x;
    __shared__ float cwp[24 * 105];        // [c8]{72 weights, 24 params}
    for (int idx = tid; idx < 24 * 96; idx += 256) {
        int c8 = idx / 96, r = idx - c8 * 96;
        float v;
        if (r < 72) {
            int i = r / 9, p = r - i * 9;
            v = wdw[(c8 * 8 + i) * 9 + p];
        } else {
            int r2 = r - 72;
            int i = r2 / 3, j = r2 - i * 3;
            int c = c8 * 8 + i;
            float A = g2[c] * BN_RSQ;
            v = (j == 0) ? A : (j == 1) ? fmaf(bdw[c], A, be2[c])
                                        : gate_c[b * 192 + c];
        }
        cwp[c8 * 105 + r] = v;
    }
    __syncthreads();
    const size_t outrow = (size_t)(b * Ln + h * Wn) * 192;
    for (int it = 0; it < 6; ++it) {
        int item = it * 256 + tid;          // 0..1535
        int w = whalf * 64 + item / 24;
        int c8 = item % 24;
        int co = c8 * 8;
        const float* wp = &cwp[c8 * 105];
        uint4 nb[3][3];
        #pragma unroll
        for (int r = 0; r < 3; ++r)
            #pragma unroll
            for (int d = 0; d < 3; ++d)
                nb[r][d] = make_uint4(0u, 0u, 0u, 0u);
        #pragma unroll
        for (int r = 0; r < 3; ++r) {
            int hh = h - 1 + r;
            if (hh < 0 || hh >= Hn) continue;
            const ushort_t* rp = fu_b + (size_t)(b * Ln + hh * Wn) * 192 + co;
            #pragma unroll
            for (int d = 0; d < 3; ++d) {
                int w2 = w - 1 + d;
                if (w2 < 0 || w2 >= Wn) continue;
                nb[r][d] = *(const uint4*)(rp + (size_t)w2 * 192);
            }
        }
        unsigned ou[4];
        #pragma unroll
        for (int i = 0; i < 8; ++i) {
            float s = 0.0f;
            #pragma unroll
            for (int r = 0; r < 3; ++r) {
                #pragma unroll
                for (int d = 0; d < 3; ++d) {
                    unsigned word = ((const unsigned*)&nb[r][d])[i >> 1];
                    float v = __uint_as_float((i & 1) ? (word & 0xffff0000u)
                                                      : (word << 16));
                    s = fmaf(wp[i * 9 + r * 3 + d], v, s);
                }
            }
            float A = wp[72 + i * 3];
            float Bc = wp[72 + i * 3 + 1];
            float G = wp[72 + i * 3 + 2];
            float y = gelu_f(fmaf(s, A, Bc)) * G;
            if (i & 1) ou[i >> 1] |= (unsigned)f2bf(y) << 16;
            else       ou[i >> 1] = (unsigned)f2bf(y);
        }
        *(uint4*)(out2b + outrow + (size_t)w * 192 + co) =
            make_uint4(ou[0], ou[1], ou[2], ou[3]);
    }
}

extern "C" void kernel_launch(void* const* d_in, const int* in_sizes, int n_in,
                              void* d_out, int out_size, void* d_ws, size_t ws_size,
                              hipStream_t stream) {
    (void)in_sizes; (void)n_in; (void)out_size; (void)ws_size;
    const float* x      = (const float*)d_in[0];
    const float* w_qkv  = (const float*)d_in[1];
    const float* b_qkv  = (const float*)d_in[2];
    const float* w_dw1  = (const float*)d_in[3];
    const float* b_dw1  = (const float*)d_in[4];
    const float* g_bn1  = (const float*)d_in[5];
    const float* be_bn1 = (const float*)d_in[6];
    const float* w_si1  = (const float*)d_in[7];
    const float* b_si1  = (const float*)d_in[8];
    const float* g_si   = (const float*)d_in[9];
    const float* be_si  = (const float*)d_in[10];
    const float* w_si2  = (const float*)d_in[11];
    const float* b_si2  = (const float*)d_in[12];
    const float* w_ci1  = (const float*)d_in[13];
    const float* b_ci1  = (const float*)d_in[14];
    const float* g_ci   = (const float*)d_in[15];
    const float* be_ci  = (const float*)d_in[16];
    const float* w_ci2  = (const float*)d_in[17];
    const float* b_ci2  = (const float*)d_in[18];
    const float* w_dw2  = (const float*)d_in[19];
    const float* b_dw2  = (const float*)d_in[20];
    const float* g_bn2  = (const float*)d_in[21];
    const float* be_bn2 = (const float*)d_in[22];
    const float* w_proj = (const float*)d_in[23];
    const float* b_proj = (const float*)d_in[24];

    float* ws = (float*)d_ws;
    ushort_t* conv1b = (ushort_t*)ws;
    ushort_t* Qp     = (ushort_t*)ws;
    ushort_t* Kp     = (ushort_t*)(ws + FUn / 2);
    ushort_t* out2b  = (ushort_t*)(ws + 8000000);
    float* gate_s    = ws + FUn;                       // B*L
    float* gate_c    = gate_s + (size_t)Bn * Ln;       // B*192
    float* pooled16  = gate_c + Bn * 192;              // B*192*16
    ushort_t* wqkvT  = (ushort_t*)(pooled16 + Bn * 192 * 16);  // 576*192 bf16
    ushort_t* wprojT = wqkvT + 576 * 192;              // 192*192 bf16
    ushort_t* xb     = (ushort_t*)d_out;
    ushort_t* fu_b   = (ushort_t*)d_out;
    ushort_t* Vp     = (ushort_t*)d_out + FUn;

    conv1_k<<<dim3(Bn * 192, 16), 256, 0, stream>>>(x, w_dw1, b_dw1, g_bn1, be_bn1,
                                                    w_qkv, w_proj,
                                                    conv1b, xb, wqkvT, wprojT, pooled16);
    gates_k<<<Bn * Hn + Bn, 192, 0, stream>>>(conv1b, pooled16,
                                              w_si1, b_si1, g_si, be_si, w_si2, b_si2,
                                              w_ci1, b_ci1, g_ci, be_ci, w_ci2, b_ci2,
                                              gate_s, gate_c);
    qkv_mfma<<<6144, 256, 0, stream>>>(xb, wqkvT, b_qkv, Qp, Kp, Vp);
    attn_mfma<<<3072, 256, 0, stream>>>(Qp, Kp, Vp, gate_s, fu_b);
    dwconv2_k<<<Bn * Hn * 2, 256, 0, stream>>>(fu_b, gate_c,
                                               w_dw2, b_dw2, g_bn2, be_bn2, out2b);
    proj_mfma<<<dim3(Mn / 128, 2), 256, 0, stream>>>(out2b, wprojT, b_proj, (float*)d_out);
}

// Round 23
// 280.367 us; speedup vs baseline: 1.0441x; 1.0012x over previous
//
#include <hip/hip_runtime.h>

#define Bn 8
#define Hn 128
#define Wn 128
#define Cn 192
#define Ln (Hn*Wn)          // 16384
#define Mn (Bn*Ln)          // 131072
#define FUn ((size_t)Mn*Cn) // 25,165,824 floats
#define BN_RSQ 0.9999950000374997f   // 1/sqrt(1+1e-5)

typedef unsigned short ushort_t;
typedef __attribute__((ext_vector_type(8))) short short8;
typedef __attribute__((ext_vector_type(4))) float f32x4;
typedef __attribute__((ext_vector_type(4))) unsigned int uint4v;

static __device__ __forceinline__ float gelu_f(float x) {
    return 0.5f * x * (1.0f + erff(x * 0.7071067811865475f));
}
static __device__ __forceinline__ float gate1p(float x) {  // 1 + sigmoid(x)
    return 1.0f + 1.0f / (1.0f + __expf(-x));
}
static __device__ __forceinline__ unsigned short f2bf(float f) {  // RNE
    unsigned u = __float_as_uint(f);
    return (unsigned short)((u + 0x7FFFu + ((u >> 16) & 1u)) >> 16);
}
static __device__ __forceinline__ unsigned int pk2(float lo, float hi) {
    return (unsigned int)f2bf(lo) | ((unsigned int)f2bf(hi) << 16);
}
static __device__ __forceinline__ float bf2f(ushort_t u) {
    return __uint_as_float((unsigned)u << 16);
}

// ==== fused qkv GEMM + window attention: block = (window, branch, head) =====
// XCD-swizzled 1D grid: g = group*48 + sib*8 + w8; sib = (head,branch).
// GEMM cols [0,96) = Q|K|V (32 each) of this head. Q/K/V staged in LDS
// (Q/K [t][40], V transposed [ch][136]); attention runs in-block.
__global__ __launch_bounds__(256) void qkvattn_mfma(const ushort_t* __restrict__ Ab,
        const ushort_t* __restrict__ BwT, const float* __restrict__ bias,
        const float* __restrict__ gate_s, ushort_t* __restrict__ fu_b)
{
    __shared__ __align__(16) ushort_t smem[128 * 64 + 96 * 64];
    ushort_t* As = smem;
    ushort_t* Bs = smem + 128 * 64;
    ushort_t* Qlds = smem;                 // 128*40 = 5120 shorts
    ushort_t* Klds = smem + 5120;          // 5120
    ushort_t* Vlds = smem + 10240;         // 32*136 = 4352
    const int g1d = blockIdx.x;            // 0..6143
    const int rem = g1d % 48;
    const int sib = rem >> 3;              // 0..5
    const int w8 = rem & 7;
    const int wid = (g1d / 48) * 8 + w8;   // b*128 + win
    const int br = sib & 1;
    const int head = sib >> 1;             // 0..2
    const int b = wid >> 7, win = wid & 127;
    int hb, wb;
    if (br == 0) { hb = (win >> 3) * 8;  wb = (win & 7) * 16; }
    else         { hb = (win >> 4) * 16; wb = (win & 15) * 8; }
    const int tid = threadIdx.x;
    const int lane = tid & 63;
    const int widx = tid >> 6;
    const int wrow = widx * 32;
    const int r0 = lane >> 4, cl = lane & 15;
    f32x4 acc[2][6] = {};

    for (int ks = 0; ks < 3; ++ks) {
        const int k0 = ks * 64;
        if (ks) __syncthreads();
        #pragma unroll
        for (int i = 0; i < 2; ++i) {
            int s = tid + i * 256;
            int row = s >> 2, q = s & 3;   // row = token t
            int l = (br == 0) ? (hb + (row >> 4)) * Wn + wb + (row & 15)
                              : (hb + (row >> 3)) * Wn + wb + (row & 7);
            const ushort_t* src = Ab + (size_t)(b * Ln + l) * 192 + k0 + q * 16;
            uint4 u0 = *(const uint4*)(src);
            uint4 u1 = *(const uint4*)(src + 8);
            int r7 = row & 7;
            *(uint4*)&As[row * 64 + (((q * 2) ^ r7) * 8)] = u0;
            *(uint4*)&As[row * 64 + (((q * 2 + 1) ^ r7) * 8)] = u1;
        }
        #pragma unroll
        for (int i = 0; i < 3; ++i) {
            int f = tid + i * 256;                    // 0..767
            int col = f % 96, kslot = f / 96;
            int part = col >> 5, ch = col & 31;
            int gcol = part * 192 + br * 96 + head * 32 + ch;
            uint4 wv = *(const uint4*)(BwT + (size_t)gcol * 192 + k0 + kslot * 8);
            *(uint4*)&Bs[col * 64 + ((kslot ^ (col & 7)) * 8)] = wv;
        }
        __syncthreads();
        #pragma unroll
        for (int kk = 0; kk < 2; ++kk) {
            int kslot = kk * 4 + r0;
            int ra0 = wrow + cl, ra1 = wrow + 16 + cl;
            short8 a0 = *(const short8*)&As[ra0 * 64 + ((kslot ^ (ra0 & 7)) * 8)];
            short8 a1 = *(const short8*)&As[ra1 * 64 + ((kslot ^ (ra1 & 7)) * 8)];
            #pragma unroll
            for (int n = 0; n < 6; ++n) {
                int col = n * 16 + cl;
                short8 bn = *(const short8*)&Bs[col * 64 + ((kslot ^ (col & 7)) * 8)];
                acc[0][n] = __builtin_amdgcn_mfma_f32_16x16x32_bf16(a0, bn, acc[0][n], 0, 0, 0);
                acc[1][n] = __builtin_amdgcn_mfma_f32_16x16x32_bf16(a1, bn, acc[1][n], 0, 0, 0);
            }
        }
    }
    float bv[6];
    #pragma unroll
    for (int n = 0; n < 6; ++n) {
        int col = n * 16 + cl;
        int part = col >> 5, ch = col & 31;
        bv[n] = bias[part * 192 + br * 96 + head * 32 + ch];
    }
    __syncthreads();                       // As/Bs reads complete everywhere
    // ---- write Q/K/V fragments to LDS ----
    #pragma unroll
    for (int m = 0; m < 2; ++m)
        #pragma unroll
        for (int n = 0; n < 6; ++n) {
            int part = n >> 1;
            int ch = (n & 1) * 16 + cl;
            #pragma unroll
            for (int j = 0; j < 4; ++j) {
                int t = wrow + m * 16 + r0 * 4 + j;
                ushort_t val = f2bf(acc[m][n][j] + bv[n]);
                if (part == 0)      Qlds[t * 40 + ch] = val;
                else if (part == 1) Klds[t * 40 + ch] = val;
                else                Vlds[ch * 136 + t] = val;
            }
        }
    __syncthreads();

    // ---- attention: wave widx handles j = widx*2 + jj ----
    const int q = cl, g = r0;
    short8 kf[8], qf[2];
    #pragma unroll
    for (int i = 0; i < 8; ++i)
        kf[i] = *(const short8*)&Klds[(16 * i + q) * 40 + 8 * g];
    #pragma unroll
    for (int jj = 0; jj < 2; ++jj)
        qf[jj] = *(const short8*)&Qlds[(16 * (widx * 2 + jj) + q) * 40 + 8 * g];
    short8 vf[2][4];
    #pragma unroll
    for (int dblk = 0; dblk < 2; ++dblk)
        #pragma unroll
        for (int s = 0; s < 4; ++s)
            vf[dblk][s] = *(const short8*)&Vlds[(16 * dblk + q) * 136 + 32 * s + 8 * g];

    const float SC = 0.5303300858899106f;   // 3/sqrt(32)
    const int cf = br * 96 + head * 32;
    const int src0 = q + ((g & 1) << 5);
    const bool thi = (g >> 1) != 0;
    const bool glo = (g < 2);
    #pragma unroll
    for (int jj = 0; jj < 2; ++jj) {
        const int j = widx * 2 + jj;
        unsigned wA[8], wB[8];
        float ss = 0.0f;
        #pragma unroll
        for (int i = 0; i < 8; ++i) {
            f32x4 z = {};
            f32x4 S = __builtin_amdgcn_mfma_f32_16x16x32_bf16(kf[i], qf[jj], z, 0, 0, 0);
            float p0 = __expf(S[0] * SC), p1 = __expf(S[1] * SC);
            float p2 = __expf(S[2] * SC), p3 = __expf(S[3] * SC);
            ss += (p0 + p1) + (p2 + p3);
            wA[i] = pk2(p0, p1);
            wB[i] = pk2(p2, p3);
        }
        ss += __shfl_xor(ss, 16);
        ss += __shfl_xor(ss, 32);
        int l_own;
        if (br == 0) l_own = (hb + j) * Wn + wb + q;
        else         l_own = (hb + 2 * j + (q >> 3)) * Wn + wb + (q & 7);
        float s_own = 3.0f * gate_s[(size_t)b * Ln + l_own] / ss;

        f32x4 O0 = {}, O1 = {};
        #pragma unroll
        for (int s = 0; s < 4; ++s) {
            unsigned a0  = (unsigned)__shfl((int)wA[2*s],     src0);
            unsigned b0  = (unsigned)__shfl((int)wB[2*s],     src0);
            unsigned a0h = (unsigned)__shfl((int)wA[2*s],     src0 + 16);
            unsigned b0h = (unsigned)__shfl((int)wB[2*s],     src0 + 16);
            unsigned a1  = (unsigned)__shfl((int)wA[2*s+1],   src0);
            unsigned b1  = (unsigned)__shfl((int)wB[2*s+1],   src0);
            unsigned a1h = (unsigned)__shfl((int)wA[2*s+1],   src0 + 16);
            unsigned b1h = (unsigned)__shfl((int)wB[2*s+1],   src0 + 16);
            uint4v B2u;
            B2u[0] = thi ? a1  : a0;
            B2u[1] = thi ? b1  : b0;
            B2u[2] = thi ? a1h : a0h;
            B2u[3] = thi ? b1h : b0h;
            short8 B2 = *(short8*)&B2u;
            O0 = __builtin_amdgcn_mfma_f32_16x16x32_bf16(vf[0][s], B2, O0, 0, 0, 0);
            O1 = __builtin_amdgcn_mfma_f32_16x16x32_bf16(vf[1][s], B2, O1, 0, 0, 0);
        }
        unsigned w0 = pk2(O0[0] * s_own, O0[1] * s_own);
        unsigned w1 = pk2(O0[2] * s_own, O0[3] * s_own);
        unsigned w2 = pk2(O1[0] * s_own, O1[1] * s_own);
        unsigned w3 = pk2(O1[2] * s_own, O1[3] * s_own);
        unsigned a0 = (unsigned)__shfl((int)w0, src0);
        unsigned a1 = (unsigned)__shfl((int)w1, src0);
        unsigned b0 = (unsigned)__shfl((int)w0, src0 + 16);
        unsigned b1 = (unsigned)__shfl((int)w1, src0 + 16);
        unsigned c0 = (unsigned)__shfl((int)w2, src0);
        unsigned c1 = (unsigned)__shfl((int)w3, src0);
        unsigned d0 = (unsigned)__shfl((int)w2, src0 + 16);
        unsigned d1 = (unsigned)__shfl((int)w3, src0 + 16);
        uint4 o = make_uint4(glo ? a0 : c0, glo ? a1 : c1,
                             glo ? b0 : d0, glo ? b1 : d1);
        *(uint4*)(fu_b + (size_t)(b * Ln + l_own) * 192 + cf + 8 * g) = o;
    }
}

// ====== proj GEMM: bf16 A (row-major) x pre-transposed bf16 B -> f32 out ====
__global__ __launch_bounds__(256) void proj_mfma(const ushort_t* __restrict__ Ab,
        const ushort_t* __restrict__ BwT, const float* __restrict__ bias,
        float* __restrict__ Cout)
{
    __shared__ __align__(16) ushort_t As[128 * 64];
    __shared__ __align__(16) ushort_t Bs[96 * 64];
    const int m0 = blockIdx.x * 128;
    const int n0 = blockIdx.y * 96;
    const int tid = threadIdx.x;
    const int lane = tid & 63;
    const int wrow = (tid >> 6) * 32;
    const int r0 = lane >> 4, cl = lane & 15;
    f32x4 acc[2][6] = {};

    for (int ks = 0; ks < 3; ++ks) {
        const int k0 = ks * 64;
        if (ks) __syncthreads();
        #pragma unroll
        for (int i = 0; i < 2; ++i) {
            int s = tid + i * 256;
            int row = s >> 2, q = s & 3;
            const ushort_t* src = Ab + (size_t)(m0 + row) * 192 + k0 + q * 16;
            uint4 u0 = *(const uint4*)(src);
            uint4 u1 = *(const uint4*)(src + 8);
            int r7 = row & 7;
            *(uint4*)&As[row * 64 + (((q * 2) ^ r7) * 8)] = u0;
            *(uint4*)&As[row * 64 + (((q * 2 + 1) ^ r7) * 8)] = u1;
        }
        #pragma unroll
        for (int i = 0; i < 3; ++i) {
            int f = tid + i * 256;
            int col = f % 96, kslot = f / 96;
            uint4 wv = *(const uint4*)(BwT + (size_t)(n0 + col) * 192 + k0 + kslot * 8);
            *(uint4*)&Bs[col * 64 + ((kslot ^ (col & 7)) * 8)] = wv;
        }
        __syncthreads();
        #pragma unroll
        for (int kk = 0; kk < 2; ++kk) {
            int kslot = kk * 4 + r0;
            int ra0 = wrow + cl, ra1 = wrow + 16 + cl;
            short8 a0 = *(const short8*)&As[ra0 * 64 + ((kslot ^ (ra0 & 7)) * 8)];
            short8 a1 = *(const short8*)&As[ra1 * 64 + ((kslot ^ (ra1 & 7)) * 8)];
            #pragma unroll
            for (int n = 0; n < 6; ++n) {
                int col = n * 16 + cl;
                short8 bn = *(const short8*)&Bs[col * 64 + ((kslot ^ (col & 7)) * 8)];
                acc[0][n] = __builtin_amdgcn_mfma_f32_16x16x32_bf16(a0, bn, acc[0][n], 0, 0, 0);
                acc[1][n] = __builtin_amdgcn_mfma_f32_16x16x32_bf16(a1, bn, acc[1][n], 0, 0, 0);
            }
        }
    }
    #pragma unroll
    for (int m = 0; m < 2; ++m) {
        #pragma unroll
        for (int n = 0; n < 6; ++n) {
            int col = n0 + n * 16 + cl;
            float bv = bias[col];
            #pragma unroll
            for (int j = 0; j < 4; ++j) {
                int row = m0 + wrow + m * 16 + r0 * 4 + j;
                Cout[(size_t)row * 192 + col] = acc[m][n][j] + bv;
            }
        }
    }
}

// ---- conv1: dwconv3x3+BN+GELU (one row/thread) + fused weight transposes ---
__global__ __launch_bounds__(256) void conv1_k(const float* __restrict__ x,
        const float* __restrict__ wdw, const float* __restrict__ bdw,
        const float* __restrict__ g1, const float* __restrict__ be1,
        const float* __restrict__ w_qkv, const float* __restrict__ w_proj,
        ushort_t* __restrict__ conv1b, ushort_t* __restrict__ xb,
        ushort_t* __restrict__ wqkvT, ushort_t* __restrict__ wprojT,
        float* __restrict__ pooled16)
{
    if (blockIdx.y == 0) {
        int gid = blockIdx.x * 256 + threadIdx.x;   // 0..393215
        if (gid < 192 * 576) {
            int k = gid / 576, n = gid - k * 576;
            wqkvT[(size_t)n * 192 + k] = f2bf(w_qkv[gid]);
        } else if (gid < 192 * 576 + 192 * 192) {
            int g2 = gid - 192 * 576;
            int k = g2 / 192, n = g2 - k * 192;
            wprojT[(size_t)n * 192 + k] = f2bf(w_proj[g2]);
        }
    }
    int bc = blockIdx.x;                   // b*192 + c
    int rg = blockIdx.y;                   // 0..15
    int c = bc % 192;
    const float* plane = x + (size_t)bc * Ln;
    int t = threadIdx.x;
    int sx = t & 31, sy = t >> 5;          // 32 strips x 8 rows
    int w0 = sx * 4, h = rg * 8 + sy;
    float wk[9];
    #pragma unroll
    for (int i = 0; i < 9; ++i) wk[i] = wdw[c * 9 + i];
    float gb = g1[c] * BN_RSQ, bb = be1[c], bd = bdw[c];

    float a[3][6];
    #pragma unroll
    for (int i = 0; i < 3; ++i) {
        int hh = h - 1 + i;
        float4 m = make_float4(0.f, 0.f, 0.f, 0.f);
        if (hh >= 0 && hh < Hn)
            m = *(const float4*)(plane + hh * Wn + w0);
        float lf = __shfl_up(m.w, 1);
        float rt = __shfl_down(m.x, 1);
        a[i][0] = sx ? lf : 0.0f;
        a[i][1] = m.x; a[i][2] = m.y; a[i][3] = m.z; a[i][4] = m.w;
        a[i][5] = (sx < 31) ? rt : 0.0f;
    }
    *(uint2*)(xb + (size_t)bc * Ln + h * Wn + w0) =
        make_uint2(pk2(a[1][1], a[1][2]), pk2(a[1][3], a[1][4]));
    float psum = 0.0f;
    float o[4];
    #pragma unroll
    for (int p = 0; p < 4; ++p) {
        float s = wk[0] * a[0][p];
        s = fmaf(wk[1], a[0][p + 1], s);
        s = fmaf(wk[2], a[0][p + 2], s);
        s = fmaf(wk[3], a[1][p],     s);
        s = fmaf(wk[4], a[1][p + 1], s);
        s = fmaf(wk[5], a[1][p + 2], s);
        s = fmaf(wk[6], a[2][p],     s);
        s = fmaf(wk[7], a[2][p + 1], s);
        s = fmaf(wk[8], a[2][p + 2], s);
        float y = gelu_f((s + bd) * gb + bb);
        psum += y;
        o[p] = y;
    }
    *(uint2*)(conv1b + (size_t)bc * Ln + h * Wn + w0) =
        make_uint2(pk2(o[0], o[1]), pk2(o[2], o[3]));
    __shared__ float red[4];
    for (int off = 32; off; off >>= 1) psum += __shfl_down(psum, off);
    if ((t & 63) == 0) red[t >> 6] = psum;
    __syncthreads();
    if (t == 0)
        pooled16[bc * 16 + rg] = red[0] + red[1] + red[2] + red[3];
}

// ------- merged gates: blocks 0..1023 spatial rows, 1024..1031 channel ------
__global__ __launch_bounds__(192) void gates_k(const ushort_t* __restrict__ conv1b,
        const float* __restrict__ pooled16,
        const float* __restrict__ ws1g, const float* __restrict__ bs1,
        const float* __restrict__ gsi, const float* __restrict__ besi,
        const float* __restrict__ ws2, const float* __restrict__ bs2,
        const float* __restrict__ w1, const float* __restrict__ b1,
        const float* __restrict__ gci, const float* __restrict__ beci,
        const float* __restrict__ w2, const float* __restrict__ b2,
        float* __restrict__ gate_s, float* __restrict__ gate_c)
{
    int blk = blockIdx.x;
    int tid = threadIdx.x;
    if (blk < Bn * Hn) {                   // ---- spatial gate row ----
        int b = blk >> 7, h = blk & 127;
        __shared__ float ws1T[192 * 24];   // [c][o]
        for (int i = tid; i < 192 * 24; i += 192) {
            int c = i / 24, o = i - c * 24;
            ws1T[i] = ws1g[o * 192 + c];
        }
        __syncthreads();
        if (tid < 128) {
            int w = tid;
            float acc24[24] = {};
            const ushort_t* base = conv1b + (size_t)b * 192 * Ln + h * Wn + w;
            #pragma unroll 4
            for (int c = 0; c < 192; ++c) {
                float v = bf2f(base[(size_t)c * Ln]);
                const float4* wp = (const float4*)&ws1T[c * 24];
                #pragma unroll
                for (int o4 = 0; o4 < 6; ++o4) {
                    float4 wv = wp[o4];
                    acc24[o4*4+0] = fmaf(v, wv.x, acc24[o4*4+0]);
                    acc24[o4*4+1] = fmaf(v, wv.y, acc24[o4*4+1]);
                    acc24[o4*4+2] = fmaf(v, wv.z, acc24[o4*4+2]);
                    acc24[o4*4+3] = fmaf(v, wv.w, acc24[o4*4+3]);
                }
            }
            float s2 = bs2[0];
            #pragma unroll
            for (int o = 0; o < 24; ++o)
                s2 = fmaf(gelu_f((acc24[o] + bs1[o]) * (gsi[o] * BN_RSQ) + besi[o]),
                          ws2[o], s2);
            gate_s[(size_t)blk * 128 + w] = gate1p(s2);
        }
    } else {                               // ---- channel gate batch ----
        int b = blk - Bn * Hn;
        __shared__ float pl[192];
        __shared__ float h1[24];
        int bc = b * 192 + tid;
        float s = 0.0f;
        #pragma unroll
        for (int i = 0; i < 16; ++i) s += pooled16[bc * 16 + i];
        pl[tid] = s * (1.0f / Ln);
        __syncthreads();
        if (tid < 24) {
            float a = b1[tid];
            for (int c = 0; c < 192; ++c) a = fmaf(pl[c], w1[tid * 192 + c], a);
            a = a * (gci[tid] * BN_RSQ) + beci[tid];
            h1[tid] = gelu_f(a);
        }
        __syncthreads();
        float a = b2[tid];
        #pragma unroll
        for (int o = 0; o < 24; ++o) a = fmaf(h1[o], w2[tid * 24 + o], a);
        gate_c[b * 192 + tid] = gate1p(a);
    }
}

// ---- dwconv2: channels-last register 3x3 stencil, conflict-free LDS -------
__global__ __launch_bounds__(256) void dwconv2_k(const ushort_t* __restrict__ fu_b,
        const float* __restrict__ gate_c,
        const float* __restrict__ wdw, const float* __restrict__ bdw,
        const float* __restrict__ g2, const float* __restrict__ be2,
        ushort_t* __restrict__ out2b)
{
    int bh = blockIdx.x >> 1;              // b*128 + h
    int whalf = blockIdx.x & 1;
    int b = bh >> 7, h = bh & 127;
    int tid = threadIdx.x;
    __shared__ float cwp[24 * 105];        // [c8]{72 weights, 24 params}
    for (int idx = tid; idx < 24 * 96; idx += 256) {
        int c8 = idx / 96, r = idx - c8 * 96;
        float v;
        if (r < 72) {
            int i = r / 9, p = r - i * 9;
            v = wdw[(c8 * 8 + i) * 9 + p];
        } else {
            int r2 = r - 72;
            int i = r2 / 3, j = r2 - i * 3;
            int c = c8 * 8 + i;
            float A = g2[c] * BN_RSQ;
            v = (j == 0) ? A : (j == 1) ? fmaf(bdw[c], A, be2[c])
                                        : gate_c[b * 192 + c];
        }
        cwp[c8 * 105 + r] = v;
    }
    __syncthreads();
    const size_t outrow = (size_t)(b * Ln + h * Wn) * 192;
    for (int it = 0; it < 6; ++it) {
        int item = it * 256 + tid;          // 0..1535
        int w = whalf * 64 + item / 24;
        int c8 = item % 24;
        int co = c8 * 8;
        const float* wp = &cwp[c8 * 105];
        uint4 nb[3][3];
        #pragma unroll
        for (int r = 0; r < 3; ++r)
            #pragma unroll
            for (int d = 0; d < 3; ++d)
                nb[r][d] = make_uint4(0u, 0u, 0u, 0u);
        #pragma unroll
        for (int r = 0; r < 3; ++r) {
            int hh = h - 1 + r;
            if (hh < 0 || hh >= Hn) continue;
            const ushort_t* rp = fu_b + (size_t)(b * Ln + hh * Wn) * 192 + co;
            #pragma unroll
            for (int d = 0; d < 3; ++d) {
                int w2 = w - 1 + d;
                if (w2 < 0 || w2 >= Wn) continue;
                nb[r][d] = *(const uint4*)(rp + (size_t)w2 * 192);
            }
        }
        unsigned ou[4];
        #pragma unroll
        for (int i = 0; i < 8; ++i) {
            float s = 0.0f;
            #pragma unroll
            for (int r = 0; r < 3; ++r) {
                #pragma unroll
                for (int d = 0; d < 3; ++d) {
                    unsigned word = ((const unsigned*)&nb[r][d])[i >> 1];
                    float v = __uint_as_float((i & 1) ? (word & 0xffff0000u)
                                                      : (word << 16));
                    s = fmaf(wp[i * 9 + r * 3 + d], v, s);
                }
            }
            float A = wp[72 + i * 3];
            float Bc = wp[72 + i * 3 + 1];
            float G = wp[72 + i * 3 + 2];
            float y = gelu_f(fmaf(s, A, Bc)) * G;
            if (i & 1) ou[i >> 1] |= (unsigned)f2bf(y) << 16;
            else       ou[i >> 1] = (unsigned)f2bf(y);
        }
        *(uint4*)(out2b + outrow + (size_t)w * 192 + co) =
            make_uint4(ou[0], ou[1], ou[2], ou[3]);
    }
}

extern "C" void kernel_launch(void* const* d_in, const int* in_sizes, int n_in,
                              void* d_out, int out_size, void* d_ws, size_t ws_size,
                              hipStream_t stream) {
    (void)in_sizes; (void)n_in; (void)out_size; (void)ws_size;
    const float* x      = (const float*)d_in[0];
    const float* w_qkv  = (const float*)d_in[1];
    const float* b_qkv  = (const float*)d_in[2];
    const float* w_dw1  = (const float*)d_in[3];
    const float* b_dw1  = (const float*)d_in[4];
    const float* g_bn1  = (const float*)d_in[5];
    const float* be_bn1 = (const float*)d_in[6];
    const float* w_si1  = (const float*)d_in[7];
    const float* b_si1  = (const float*)d_in[8];
    const float* g_si   = (const float*)d_in[9];
    const float* be_si  = (const float*)d_in[10];
    const float* w_si2  = (const float*)d_in[11];
    const float* b_si2  = (const float*)d_in[12];
    const float* w_ci1  = (const float*)d_in[13];
    const float* b_ci1  = (const float*)d_in[14];
    const float* g_ci   = (const float*)d_in[15];
    const float* be_ci  = (const float*)d_in[16];
    const float* w_ci2  = (const float*)d_in[17];
    const float* b_ci2  = (const float*)d_in[18];
    const float* w_dw2  = (const float*)d_in[19];
    const float* b_dw2  = (const float*)d_in[20];
    const float* g_bn2  = (const float*)d_in[21];
    const float* be_bn2 = (const float*)d_in[22];
    const float* w_proj = (const float*)d_in[23];
    const float* b_proj = (const float*)d_in[24];

    // ws (f32 units):
    //   [0, FUn/2):      conv1b bf16 (phase A) -> fu_b bf16 (phase B)
    //   [FUn/2, FUn):    out2b bf16 (phase C)
    //   [FUn, ...):      gate_s, gate_c, pooled16, wqkvT, wprojT
    // d_out (shorts): xb [0, FUn) [conv1 -> fused]; proj overwrites all (f32).
    float* ws = (float*)d_ws;
    ushort_t* conv1b = (ushort_t*)ws;
    ushort_t* fu_b   = (ushort_t*)ws;
    ushort_t* out2b  = (ushort_t*)(ws + FUn / 2);
    float* gate_s    = ws + FUn;                       // B*L
    float* gate_c    = gate_s + (size_t)Bn * Ln;       // B*192
    float* pooled16  = gate_c + Bn * 192;              // B*192*16
    ushort_t* wqkvT  = (ushort_t*)(pooled16 + Bn * 192 * 16);  // 576*192 bf16
    ushort_t* wprojT = wqkvT + 576 * 192;              // 192*192 bf16
    ushort_t* xb     = (ushort_t*)d_out;

    conv1_k<<<dim3(Bn * 192, 16), 256, 0, stream>>>(x, w_dw1, b_dw1, g_bn1, be_bn1,
                                                    w_qkv, w_proj,
                                                    conv1b, xb, wqkvT, wprojT, pooled16);
    gates_k<<<Bn * Hn + Bn, 192, 0, stream>>>(conv1b, pooled16,
                                              w_si1, b_si1, g_si, be_si, w_si2, b_si2,
                                              w_ci1, b_ci1, g_ci, be_ci, w_ci2, b_ci2,
                                              gate_s, gate_c);
    qkvattn_mfma<<<6144, 256, 0, stream>>>(xb, wqkvT, b_qkv, gate_s, fu_b);
    dwconv2_k<<<Bn * Hn * 2, 256, 0, stream>>>(fu_b, gate_c,
                                               w_dw2, b_dw2, g_bn2, be_bn2, out2b);
    proj_mfma<<<dim3(Mn / 128, 2), 256, 0, stream>>>(out2b, wprojT, b_proj, (float*)d_out);
}